// Round 5
// baseline (8588.837 us; speedup 1.0000x reference)
//
#include <hip/hip_runtime.h>
#include <hip/hip_cooperative_groups.h>
#include <hip/hip_bf16.h>
#include <math.h>

#define CMDN   2
#define LIDARN 360
#define HN     256
#define TN     50
#define BATCH  2048
#define KXN    362              // CMD+LIDAR
#define NG     1024             // 4*H gate columns
#define KP     384              // padded x-K for big GEMMs
#define MR     (TN*BATCH)       // 102400 rows (t-major: r = t*2048 + b)
#define SLAB   ((size_t)BATCH*HN)

typedef __attribute__((ext_vector_type(8))) short bf16x8;
typedef __attribute__((ext_vector_type(4))) float f32x4;

__device__ inline unsigned short f2b(float f) {
    unsigned int x = __builtin_bit_cast(unsigned int, f);
    x += 0x7FFFu + ((x >> 16) & 1u);
    return (unsigned short)(x >> 16);
}
__device__ inline float b2f(unsigned short u) {
    unsigned int x = ((unsigned int)u) << 16;
    return __builtin_bit_cast(float, x);
}
__device__ inline float sigf(float x)  { return 1.f / (1.f + __expf(-x)); }
__device__ inline float tanhfa(float x){ return 2.f / (1.f + __expf(-2.f * x)) - 1.f; }

// packed gate-col order: p = 4*u + g  ->  original row jorig = g*256 + u
__device__ inline int p2j(int p) { return ((p & 3) << 8) + (p >> 2); }

// ---------------------------------------------------------------------------
// 128x128 MFMA GEMM with chunked XCD swizzle.
// AMODE 0: A bf16 [M][K].  AMODE 1: A = past fp32 with (b,t) remap + zero-pad.
// OMODE 0: C f32 = acc+bias. OMODE 1: outproj remap to out[b][t][col], col<360.
// OMODE 2: C bf16 = acc+bias.
// ---------------------------------------------------------------------------
template<int OMODE, int AMODE>
__global__ __launch_bounds__(256) void gemm128(
    const unsigned short* __restrict__ A,
    const float* __restrict__ Af,
    const unsigned short* __restrict__ B,
    const float* __restrict__ bias,
    void* __restrict__ Cv,
    int K, int ldc)
{
    __shared__ __align__(16) unsigned short As[128][40];
    __shared__ __align__(16) unsigned short Bs[128][40];

    // chunked XCD swizzle (nwg % 8 == 0 for all our grids)
    const int nwg = gridDim.x * gridDim.y;
    const int hid = blockIdx.y * gridDim.x + blockIdx.x;
    const int lid = (hid & 7) * (nwg >> 3) + (hid >> 3);
    const int bx  = lid % gridDim.x;
    const int by  = lid / gridDim.x;

    const int tid  = threadIdx.x;
    const int lane = tid & 63;
    const int wv   = tid >> 6;
    const int wm   = wv >> 1, wn = wv & 1;      // 2x2 waves, each 64x64
    const int r0   = by * 128;
    const int n0   = bx * 128;
    const int l15  = lane & 15;
    const int kb   = (lane >> 4) << 3;
    const int row1 = tid >> 2, q1 = tid & 3;

    f32x4 acc[4][4] = {};

    for (int k0 = 0; k0 < K; k0 += 32) {
        if (AMODE == 0) {
            *(bf16x8*)&As[row1][q1 * 8] =
                *(const bf16x8*)&A[(size_t)(r0 + row1) * K + k0 + q1 * 8];
            *(bf16x8*)&As[row1 + 64][q1 * 8] =
                *(const bf16x8*)&A[(size_t)(r0 + row1 + 64) * K + k0 + q1 * 8];
        } else {
            #pragma unroll
            for (int hh = 0; hh < 2; ++hh) {
                const int r  = r0 + row1 + hh * 64;
                const int tt = r >> 11, bb = r & 2047;
                const float* p = Af + ((size_t)bb * TN + tt) * KXN;
                const int kbase = k0 + q1 * 8;
                bf16x8 v;
                if (kbase + 8 <= KXN) {
                    float2 f0 = *(const float2*)(p + kbase);
                    float2 f1 = *(const float2*)(p + kbase + 2);
                    float2 f2 = *(const float2*)(p + kbase + 4);
                    float2 f3 = *(const float2*)(p + kbase + 6);
                    v[0] = (short)f2b(f0.x); v[1] = (short)f2b(f0.y);
                    v[2] = (short)f2b(f1.x); v[3] = (short)f2b(f1.y);
                    v[4] = (short)f2b(f2.x); v[5] = (short)f2b(f2.y);
                    v[6] = (short)f2b(f3.x); v[7] = (short)f2b(f3.y);
                } else {
                    #pragma unroll
                    for (int e = 0; e < 8; ++e) {
                        int k = kbase + e;
                        v[e] = (k < KXN) ? (short)f2b(p[k]) : (short)0;
                    }
                }
                *(bf16x8*)&As[row1 + hh * 64][q1 * 8] = v;
            }
        }
        *(bf16x8*)&Bs[row1][q1 * 8] =
            *(const bf16x8*)&B[(size_t)(n0 + row1) * K + k0 + q1 * 8];
        *(bf16x8*)&Bs[row1 + 64][q1 * 8] =
            *(const bf16x8*)&B[(size_t)(n0 + row1 + 64) * K + k0 + q1 * 8];
        __syncthreads();
        bf16x8 a[4], b[4];
        #pragma unroll
        for (int i = 0; i < 4; ++i) {
            a[i] = *(const bf16x8*)&As[wm * 64 + i * 16 + l15][kb];
            b[i] = *(const bf16x8*)&Bs[wn * 64 + i * 16 + l15][kb];
        }
        #pragma unroll
        for (int mi = 0; mi < 4; ++mi)
            #pragma unroll
            for (int ni = 0; ni < 4; ++ni)
                acc[mi][ni] = __builtin_amdgcn_mfma_f32_16x16x32_bf16(a[mi], b[ni], acc[mi][ni], 0, 0, 0);
        __syncthreads();
    }

    #pragma unroll
    for (int mi = 0; mi < 4; ++mi) {
        const int rowb = r0 + wm * 64 + mi * 16 + ((lane >> 4) << 2);
        #pragma unroll
        for (int ni = 0; ni < 4; ++ni) {
            const int col = n0 + wn * 64 + ni * 16 + l15;
            #pragma unroll
            for (int r = 0; r < 4; ++r) {
                const int row = rowb + r;
                float v = acc[mi][ni][r];
                if (OMODE == 0) {
                    ((float*)Cv)[(size_t)row * ldc + col] = v + bias[col];
                } else if (OMODE == 2) {
                    ((unsigned short*)Cv)[(size_t)row * ldc + col] = f2b(v + bias[col]);
                } else {
                    if (col < LIDARN) {
                        int t = row >> 11, b = row & 2047;
                        ((float*)Cv)[(size_t)b * (TN * LIDARN) + (size_t)t * LIDARN + col] = v + bias[col];
                    }
                }
            }
        }
    }
}

// ---------------------------------------------------------------------------
// Persistent cooperative kernel: all 100 recurrent steps.
// Grid (8,32) = 256 blocks x 512 threads, 1 block/CU.
// Block: 64 batch rows (r0) x 128 gate cols (pb). W tile resident in LDS,
// c-state resident in registers. One grid.sync per step.
// ---------------------------------------------------------------------------
__global__ __launch_bounds__(512, 2) void recurrent_all(
    const unsigned short* __restrict__ xw,     // [50][2048][1024] enc additive (incl eb)
    const float* __restrict__ l0w,             // [2048][1024] dec0 additive (incl db)
    const float* __restrict__ biasf,           // [1024] folded dec bias
    const float* __restrict__ cmdw,            // [1024][2]
    const float* __restrict__ cmds,            // [2048][50][2] fp32
    const unsigned short* __restrict__ Wenc,   // [1024][256] packed p-order
    const unsigned short* __restrict__ Wdhh,
    const unsigned short* __restrict__ Wcomb,
    unsigned short* __restrict__ h0,           // [2048][256] bf16, zeroed
    unsigned short* __restrict__ h1,
    unsigned short* __restrict__ hdec)         // [50][2048][256] bf16
{
    __shared__ __align__(16) unsigned short Wl[128][264];
    __shared__ __align__(16) unsigned short Hl[64][264];

    const int tid  = threadIdx.x;
    const int lane = tid & 63;
    const int wv   = tid >> 6;           // 0..7
    const int wm   = wv >> 2;            // 0..1  (row half)
    const int wn   = wv & 3;             // 0..3  (col quarter)
    const int r0   = blockIdx.y * 64;
    const int pb   = blockIdx.x * 128;
    const int l15  = lane & 15;
    const int kb   = (lane >> 4) << 3;
    const int g    = l15 & 3;            // 0=i 1=f 2=g 3=o

    cooperative_groups::grid_group grid = cooperative_groups::this_grid();

    // per-lane constants
    int pcol[2]; float w0c[2], w1c[2], bfv[2];
    #pragma unroll
    for (int ni = 0; ni < 2; ++ni) {
        pcol[ni] = pb + wn * 32 + ni * 16 + l15;
        w0c[ni] = cmdw[pcol[ni] * 2];
        w1c[ni] = cmdw[pcol[ni] * 2 + 1];
        bfv[ni] = biasf[pcol[ni]];
    }
    int rowv[2][4];
    #pragma unroll
    for (int mi = 0; mi < 2; ++mi)
        #pragma unroll
        for (int r = 0; r < 4; ++r)
            rowv[mi][r] = r0 + wm * 32 + mi * 16 + ((lane >> 4) << 2) + r;

    float c_reg[2][2][4] = {};

    auto stage_W = [&](const unsigned short* W) {
        const int row = tid >> 2, q = tid & 3;
        #pragma unroll
        for (int cch = 0; cch < 8; ++cch) {
            const int col = (cch * 4 + q) * 8;
            *(bf16x8*)&Wl[row][col] = *(const bf16x8*)&W[(size_t)(pb + row) * HN + col];
        }
    };

    // mode 0: enc (additive = xw_t bf16); mode 1: dec0 (l0w f32 + cmd);
    // mode 2: dec (biasf + cmd). One grid.sync at the end.
    auto do_step = [&](int mode, int t, const unsigned short* hsrc, unsigned short* hdst) {
        {   // stage h tile
            const int row = tid >> 3, q = tid & 7;
            #pragma unroll
            for (int cch = 0; cch < 4; ++cch) {
                const int col = (cch * 8 + q) * 8;
                *(bf16x8*)&Hl[row][col] = *(const bf16x8*)&hsrc[(size_t)(r0 + row) * HN + col];
            }
        }
        // additive prefetch (independent of LDS)
        float addv[2][2][4];
        if (mode == 0) {
            const unsigned short* xwt = xw + (size_t)t * BATCH * NG;
            #pragma unroll
            for (int mi = 0; mi < 2; ++mi)
                #pragma unroll
                for (int r = 0; r < 4; ++r) {
                    const size_t rb = (size_t)rowv[mi][r] * NG;
                    #pragma unroll
                    for (int ni = 0; ni < 2; ++ni)
                        addv[mi][ni][r] = b2f(xwt[rb + pcol[ni]]);
                }
        } else {
            #pragma unroll
            for (int mi = 0; mi < 2; ++mi)
                #pragma unroll
                for (int r = 0; r < 4; ++r) {
                    const int row = rowv[mi][r];
                    const float* cp = cmds + ((size_t)row * TN + t) * CMDN;
                    const float c0 = cp[0], c1 = cp[1];
                    #pragma unroll
                    for (int ni = 0; ni < 2; ++ni) {
                        float base = (mode == 1) ? l0w[(size_t)row * NG + pcol[ni]] : bfv[ni];
                        addv[mi][ni][r] = base + c0 * w0c[ni] + c1 * w1c[ni];
                    }
                }
        }
        __syncthreads();

        f32x4 acc[2][2] = {};
        #pragma unroll
        for (int kc = 0; kc < 8; ++kc) {
            const int kf = kc * 32 + kb;
            bf16x8 a0 = *(const bf16x8*)&Hl[wm * 32 +      l15][kf];
            bf16x8 a1 = *(const bf16x8*)&Hl[wm * 32 + 16 + l15][kf];
            bf16x8 b0 = *(const bf16x8*)&Wl[wn * 32 +      l15][kf];
            bf16x8 b1 = *(const bf16x8*)&Wl[wn * 32 + 16 + l15][kf];
            acc[0][0] = __builtin_amdgcn_mfma_f32_16x16x32_bf16(a0, b0, acc[0][0], 0, 0, 0);
            acc[0][1] = __builtin_amdgcn_mfma_f32_16x16x32_bf16(a0, b1, acc[0][1], 0, 0, 0);
            acc[1][0] = __builtin_amdgcn_mfma_f32_16x16x32_bf16(a1, b0, acc[1][0], 0, 0, 0);
            acc[1][1] = __builtin_amdgcn_mfma_f32_16x16x32_bf16(a1, b1, acc[1][1], 0, 0, 0);
        }

        // fused cell
        #pragma unroll
        for (int mi = 0; mi < 2; ++mi)
            #pragma unroll
            for (int ni = 0; ni < 2; ++ni)
                #pragma unroll
                for (int r = 0; r < 4; ++r) {
                    float v   = acc[mi][ni][r] + addv[mi][ni][r];
                    float act = (g == 2) ? tanhfa(v) : sigf(v);
                    float a1  = __shfl_xor(act, 1);
                    float a2  = __shfl_xor(act, 2);
                    float a3  = __shfl_xor(act, 3);
                    if (g == 0) {                   // lane holds i; a1=f, a2=g, a3=o
                        float cc = a1 * c_reg[mi][ni][r] + act * a2;
                        c_reg[mi][ni][r] = cc;
                        hdst[(size_t)rowv[mi][r] * HN + (pcol[ni] >> 2)] = f2b(a3 * tanhfa(cc));
                    }
                }
        __threadfence();
        grid.sync();
    };

    stage_W(Wenc);
    __syncthreads();
    for (int t = 0; t < TN; ++t) {
        const unsigned short* src = (t & 1) ? h1 : h0;
        unsigned short*       dst = (t & 1) ? h0 : h1;
        do_step(0, t, src, dst);            // final h lands in h0 (t=49 odd)
    }

    stage_W(Wdhh);
    __syncthreads();
    do_step(1, 0, h0, hdec);

    stage_W(Wcomb);
    __syncthreads();
    for (int t = 1; t < TN; ++t)
        do_step(2, t, hdec + (size_t)(t - 1) * SLAB, hdec + (size_t)t * SLAB);
}

// ---------------------------------------------------------------------------
// Packs / folds (one-time)
// ---------------------------------------------------------------------------
__global__ __launch_bounds__(256) void pack_w(
    const float* __restrict__ past,
    const float* __restrict__ eWih, const float* __restrict__ eWhh, const float* __restrict__ eb,
    const float* __restrict__ dWih, const float* __restrict__ dWhh, const float* __restrict__ db,
    const float* __restrict__ oW,
    unsigned short* __restrict__ L0b,      // [2048][384]
    unsigned short* __restrict__ Wihe_p,   // [1024][384]
    unsigned short* __restrict__ Wdihl_p,  // [1024][384]
    unsigned short* __restrict__ Whhe_p,   // [1024][256]
    unsigned short* __restrict__ Wdhh_p,   // [1024][256]
    unsigned short* __restrict__ oWp,      // [384][256]
    float* __restrict__ Wc_p,              // [1024][2]
    float* __restrict__ ebp, float* __restrict__ dbp)
{
    int idx = blockIdx.x * 256 + threadIdx.x;
    if (idx < BATCH * KP) {                // L0b: lidar0 = past[:, -1, 2:]
        int b = idx / KP, k = idx - b * KP;
        L0b[idx] = (k < LIDARN)
            ? f2b(past[((size_t)b * TN + (TN - 1)) * KXN + CMDN + k]) : (unsigned short)0;
    }
    if (idx < NG * KP) {
        int p = idx / KP, k = idx - p * KP;
        int j = p2j(p);
        Wihe_p[idx]  = (k < KXN)    ? f2b(eWih[(size_t)j * KXN + k]) : (unsigned short)0;
        Wdihl_p[idx] = (k < LIDARN) ? f2b(dWih[(size_t)j * KXN + k]) : (unsigned short)0;
        if (k < HN) {
            Whhe_p[p * HN + k] = f2b(eWhh[(size_t)j * HN + k]);
            Wdhh_p[p * HN + k] = f2b(dWhh[(size_t)j * HN + k]);
        }
        if (k < 2) Wc_p[p * 2 + k] = dWih[(size_t)j * KXN + LIDARN + k];
        if (k == 0) { ebp[p] = eb[j]; dbp[p] = db[j]; }
    }
    if (idx < KP * HN) {
        int n = idx / HN, k = idx - n * HN;
        oWp[idx] = (n < LIDARN) ? f2b(oW[(size_t)n * HN + k]) : (unsigned short)0;
    }
}

// Wcomb[p][k] = dWhh[j][k] + sum_n dWih[j][n] * oW[n][k]
__global__ __launch_bounds__(256) void wcomb_kernel(
    const float* __restrict__ dWih, const float* __restrict__ dWhh,
    const float* __restrict__ oW, unsigned short* __restrict__ Wcomb_p)
{
    int p = blockIdx.x, k = threadIdx.x;
    int j = p2j(p);
    float s = dWhh[(size_t)j * HN + k];
    for (int n = 0; n < LIDARN; ++n)
        s += dWih[(size_t)j * KXN + n] * oW[(size_t)n * HN + k];
    Wcomb_p[(size_t)p * HN + k] = f2b(s);
}

// biasf[p] = db[j] + sum_n dWih[j][n] * ob[n]
__global__ __launch_bounds__(256) void biasf_kernel(
    const float* __restrict__ dWih, const float* __restrict__ db,
    const float* __restrict__ ob, float* __restrict__ biasf)
{
    int p = blockIdx.x * 256 + threadIdx.x;
    if (p >= NG) return;
    int j = p2j(p);
    float s = db[j];
    for (int n = 0; n < LIDARN; ++n)
        s += dWih[(size_t)j * KXN + n] * ob[n];
    biasf[p] = s;
}

__global__ __launch_bounds__(256) void init_h(unsigned short* __restrict__ h0)
{
    int idx = blockIdx.x * 256 + threadIdx.x;
    if (idx < BATCH * HN) h0[idx] = 0;
}

extern "C" void kernel_launch(void* const* d_in, const int* in_sizes, int n_in,
                              void* d_out, int out_size, void* d_ws, size_t ws_size,
                              hipStream_t stream)
{
    const float* past = (const float*)d_in[0];
    const float* cmds = (const float*)d_in[1];
    const float* eWih = (const float*)d_in[2];
    const float* eWhh = (const float*)d_in[3];
    const float* eb   = (const float*)d_in[4];
    const float* dWih = (const float*)d_in[5];
    const float* dWhh = (const float*)d_in[6];
    const float* db   = (const float*)d_in[7];
    const float* oW   = (const float*)d_in[8];
    const float* ob   = (const float*)d_in[9];
    float* out = (float*)d_out;

    char* w = (char*)d_ws;
    auto alloc = [&](size_t bytes) {
        char* p = w; w += (bytes + 255) & ~(size_t)255; return p;
    };
    unsigned short* xw      = (unsigned short*)alloc((size_t)MR * NG * 2);   // 209.7 MB
    unsigned short* hdec    = (unsigned short*)alloc((size_t)MR * HN * 2);   // 52.4 MB
    float*          l0w     = (float*)alloc((size_t)BATCH * NG * 4);         // 8.4 MB
    unsigned short* L0b     = (unsigned short*)alloc((size_t)BATCH * KP * 2);
    unsigned short* Wihe_p  = (unsigned short*)alloc((size_t)NG * KP * 2);
    unsigned short* Wdihl_p = (unsigned short*)alloc((size_t)NG * KP * 2);
    unsigned short* Whhe_p  = (unsigned short*)alloc((size_t)NG * HN * 2);
    unsigned short* Wdhh_p  = (unsigned short*)alloc((size_t)NG * HN * 2);
    unsigned short* Wcomb_p = (unsigned short*)alloc((size_t)NG * HN * 2);
    unsigned short* oWp     = (unsigned short*)alloc((size_t)KP * HN * 2);
    float*          Wc_p    = (float*)alloc((size_t)NG * 2 * 4);
    float*          ebp     = (float*)alloc(NG * 4);
    float*          dbp     = (float*)alloc(NG * 4);
    float*          biasf   = (float*)alloc(NG * 4);
    unsigned short* h0      = (unsigned short*)alloc(SLAB * 2);
    unsigned short* h1      = (unsigned short*)alloc(SLAB * 2);

    pack_w<<<(BATCH * KP + 255) / 256, 256, 0, stream>>>(
        past, eWih, eWhh, eb, dWih, dWhh, db, oW,
        L0b, Wihe_p, Wdihl_p, Whhe_p, Wdhh_p, oWp, Wc_p, ebp, dbp);
    wcomb_kernel<<<NG, 256, 0, stream>>>(dWih, dWhh, oW, Wcomb_p);
    biasf_kernel<<<(NG + 255) / 256, 256, 0, stream>>>(dWih, db, ob, biasf);
    init_h<<<(BATCH * HN + 255) / 256, 256, 0, stream>>>(h0);

    // xw = pack(past) @ Wihe^T + eb  (fused A-pack, bf16 out, t-major rows)
    gemm128<2, 1><<<dim3(NG / 128, MR / 128), 256, 0, stream>>>(
        nullptr, past, Wihe_p, ebp, xw, KP, NG);
    // l0w = lidar0 @ Wl^T + db (f32)
    gemm128<0, 0><<<dim3(NG / 128, BATCH / 128), 256, 0, stream>>>(
        L0b, nullptr, Wdihl_p, dbp, l0w, KP, NG);

    // all 100 recurrent steps in one cooperative kernel
    {
        const unsigned short* xw_c = xw;  const float* l0w_c = l0w;
        const float* biasf_c = biasf;     const float* cmdw_c = Wc_p;
        const float* cmds_c = cmds;
        const unsigned short* we = Whhe_p, *wd = Wdhh_p, *wc = Wcomb_p;
        unsigned short* h0_ = h0; unsigned short* h1_ = h1; unsigned short* hd_ = hdec;
        void* args[] = {
            (void*)&xw_c, (void*)&l0w_c, (void*)&biasf_c, (void*)&cmdw_c, (void*)&cmds_c,
            (void*)&we, (void*)&wd, (void*)&wc,
            (void*)&h0_, (void*)&h1_, (void*)&hd_
        };
        hipLaunchCooperativeKernel(reinterpret_cast<void*>(recurrent_all),
                                   dim3(8, 32), dim3(512), args, 0, stream);
    }

    // out[b][t][n] = hdec[t][b] @ oW^T + ob
    gemm128<1, 0><<<dim3(KP / 128, MR / 128), 256, 0, stream>>>(
        hdec, nullptr, oWp, ob, out, HN, 0);
}

// Round 6
// 2158.448 us; speedup vs baseline: 3.9792x; 3.9792x over previous
//
#include <hip/hip_runtime.h>
#include <hip/hip_bf16.h>
#include <math.h>

#define CMDN   2
#define LIDARN 360
#define HN     256
#define TN     50
#define BATCH  2048
#define KXN    362              // CMD+LIDAR
#define NG     1024             // 4*H gate columns
#define KP     384              // padded x-K for big GEMMs
#define MR     (TN*BATCH)       // 102400 rows (t-major: r = t*2048 + b)

typedef __attribute__((ext_vector_type(8))) short bf16x8;
typedef __attribute__((ext_vector_type(4))) float f32x4;

__device__ inline unsigned short f2b(float f) {
    unsigned int x = __builtin_bit_cast(unsigned int, f);
    x += 0x7FFFu + ((x >> 16) & 1u);
    return (unsigned short)(x >> 16);
}
__device__ inline float b2f(unsigned short u) {
    unsigned int x = ((unsigned int)u) << 16;
    return __builtin_bit_cast(float, x);
}
__device__ inline float sigf(float x)  { return 1.f / (1.f + __expf(-x)); }
__device__ inline float tanhfa(float x){ return 2.f / (1.f + __expf(-2.f * x)) - 1.f; }

// packed gate-col order: p = 4*u + g  ->  original row jorig = g*256 + u
__device__ inline int p2j(int p) { return ((p & 3) << 8) + (p >> 2); }

// ---------------------------------------------------------------------------
// 128x128 MFMA GEMM with chunked XCD swizzle (unchanged from round 5 — proven).
// AMODE 0: A bf16 [M][K].  AMODE 1: A = past fp32 with (b,t) remap + zero-pad.
// OMODE 0: C f32 = acc+bias. OMODE 1: outproj remap to out[b][t][col], col<360.
// OMODE 2: C bf16 = acc+bias.
// ---------------------------------------------------------------------------
template<int OMODE, int AMODE>
__global__ __launch_bounds__(256) void gemm128(
    const unsigned short* __restrict__ A,
    const float* __restrict__ Af,
    const unsigned short* __restrict__ B,
    const float* __restrict__ bias,
    void* __restrict__ Cv,
    int K, int ldc)
{
    __shared__ __align__(16) unsigned short As[128][40];
    __shared__ __align__(16) unsigned short Bs[128][40];

    const int nwg = gridDim.x * gridDim.y;
    const int hid = blockIdx.y * gridDim.x + blockIdx.x;
    const int lid = (hid & 7) * (nwg >> 3) + (hid >> 3);
    const int bx  = lid % gridDim.x;
    const int by  = lid / gridDim.x;

    const int tid  = threadIdx.x;
    const int lane = tid & 63;
    const int wv   = tid >> 6;
    const int wm   = wv >> 1, wn = wv & 1;
    const int r0   = by * 128;
    const int n0   = bx * 128;
    const int l15  = lane & 15;
    const int kb   = (lane >> 4) << 3;
    const int row1 = tid >> 2, q1 = tid & 3;

    f32x4 acc[4][4] = {};

    for (int k0 = 0; k0 < K; k0 += 32) {
        if (AMODE == 0) {
            *(bf16x8*)&As[row1][q1 * 8] =
                *(const bf16x8*)&A[(size_t)(r0 + row1) * K + k0 + q1 * 8];
            *(bf16x8*)&As[row1 + 64][q1 * 8] =
                *(const bf16x8*)&A[(size_t)(r0 + row1 + 64) * K + k0 + q1 * 8];
        } else {
            #pragma unroll
            for (int hh = 0; hh < 2; ++hh) {
                const int r  = r0 + row1 + hh * 64;
                const int tt = r >> 11, bb = r & 2047;
                const float* p = Af + ((size_t)bb * TN + tt) * KXN;
                const int kbase = k0 + q1 * 8;
                bf16x8 v;
                if (kbase + 8 <= KXN) {
                    float2 f0 = *(const float2*)(p + kbase);
                    float2 f1 = *(const float2*)(p + kbase + 2);
                    float2 f2 = *(const float2*)(p + kbase + 4);
                    float2 f3 = *(const float2*)(p + kbase + 6);
                    v[0] = (short)f2b(f0.x); v[1] = (short)f2b(f0.y);
                    v[2] = (short)f2b(f1.x); v[3] = (short)f2b(f1.y);
                    v[4] = (short)f2b(f2.x); v[5] = (short)f2b(f2.y);
                    v[6] = (short)f2b(f3.x); v[7] = (short)f2b(f3.y);
                } else {
                    #pragma unroll
                    for (int e = 0; e < 8; ++e) {
                        int k = kbase + e;
                        v[e] = (k < KXN) ? (short)f2b(p[k]) : (short)0;
                    }
                }
                *(bf16x8*)&As[row1 + hh * 64][q1 * 8] = v;
            }
        }
        *(bf16x8*)&Bs[row1][q1 * 8] =
            *(const bf16x8*)&B[(size_t)(n0 + row1) * K + k0 + q1 * 8];
        *(bf16x8*)&Bs[row1 + 64][q1 * 8] =
            *(const bf16x8*)&B[(size_t)(n0 + row1 + 64) * K + k0 + q1 * 8];
        __syncthreads();
        bf16x8 a[4], b[4];
        #pragma unroll
        for (int i = 0; i < 4; ++i) {
            a[i] = *(const bf16x8*)&As[wm * 64 + i * 16 + l15][kb];
            b[i] = *(const bf16x8*)&Bs[wn * 64 + i * 16 + l15][kb];
        }
        #pragma unroll
        for (int mi = 0; mi < 4; ++mi)
            #pragma unroll
            for (int ni = 0; ni < 4; ++ni)
                acc[mi][ni] = __builtin_amdgcn_mfma_f32_16x16x32_bf16(a[mi], b[ni], acc[mi][ni], 0, 0, 0);
        __syncthreads();
    }

    #pragma unroll
    for (int mi = 0; mi < 4; ++mi) {
        const int rowb = r0 + wm * 64 + mi * 16 + ((lane >> 4) << 2);
        #pragma unroll
        for (int ni = 0; ni < 4; ++ni) {
            const int col = n0 + wn * 64 + ni * 16 + l15;
            #pragma unroll
            for (int r = 0; r < 4; ++r) {
                const int row = rowb + r;
                float v = acc[mi][ni][r];
                if (OMODE == 0) {
                    ((float*)Cv)[(size_t)row * ldc + col] = v + bias[col];
                } else if (OMODE == 2) {
                    ((unsigned short*)Cv)[(size_t)row * ldc + col] = f2b(v + bias[col]);
                } else {
                    if (col < LIDARN) {
                        int t = row >> 11, b = row & 2047;
                        ((float*)Cv)[(size_t)b * (TN * LIDARN) + (size_t)t * LIDARN + col] = v + bias[col];
                    }
                }
            }
        }
    }
}

// ---------------------------------------------------------------------------
// Persistent recurrence, NO cross-block sync. 128 blocks x 512 threads.
// Block owns 16 batch rows x ALL 1024 gate cols. h lives in LDS (ping-pong),
// c in registers. W streamed per step from L2 in fragment-packed order
// (coalesced 16B/lane, direct to B-frag registers).
// Wave w (0..7) owns cols [w*128, w*128+128): cfrag = w*8+ni.
// ---------------------------------------------------------------------------
__global__ __launch_bounds__(512) void recur_persist(
    const unsigned short* __restrict__ xw,      // [50][2048][1024] bf16 (x@Wih+eb)
    const float* __restrict__ l0w,              // [2048][1024] f32 (lidar0@Wl+db)
    const float* __restrict__ biasf,            // [1024] folded dec bias
    const float* __restrict__ cmdw,             // [1024][2]
    const float* __restrict__ cmds,             // [2048][50][2] f32
    const unsigned short* __restrict__ Wf_enc,  // frag-packed [64cf][8kf][64lane][8]
    const unsigned short* __restrict__ Wf_dec0,
    const unsigned short* __restrict__ Wf_dec,
    unsigned short* __restrict__ hdec)          // [50][2048][256] bf16
{
    __shared__ __align__(16) unsigned short Hl[2][16][264];
    __shared__ __align__(16) unsigned short Xl[16 * 1024];

    const int tid  = threadIdx.x;
    const int lane = tid & 63;
    const int w    = tid >> 6;           // wave 0..7
    const int l15  = lane & 15;
    const int lhi  = lane >> 4;          // 0..3
    const int g    = l15 & 3;            // gate 0=i 1=f 2=g 3=o
    const int r0   = blockIdx.x * 16;    // batch rows

    // zero Hl[0] (h0 = 0)
    for (int i = tid; i < 16 * 264; i += 512)
        ((unsigned short*)Hl[0])[i] = 0;
    __syncthreads();

    // per-lane decoder constants (col p = w*128 + ni*16 + l15)
    float bf_r[8], w0_r[8], w1_r[8];
    #pragma unroll
    for (int ni = 0; ni < 8; ++ni) {
        const int p = w * 128 + ni * 16 + l15;
        bf_r[ni] = biasf[p];
        w0_r[ni] = cmdw[p * 2];
        w1_r[ni] = cmdw[p * 2 + 1];
    }

    float c_reg[8][4] = {};
    int cur = 0;
    f32x4 acc[8];

    auto kloop = [&](const unsigned short* __restrict__ Wf) {
        #pragma unroll
        for (int ni = 0; ni < 8; ++ni) acc[ni] = f32x4{0.f, 0.f, 0.f, 0.f};
        #pragma unroll
        for (int kf = 0; kf < 8; ++kf) {
            bf16x8 a = *(const bf16x8*)&Hl[cur][l15][kf * 32 + lhi * 8];
            #pragma unroll
            for (int ni = 0; ni < 8; ++ni) {
                bf16x8 b = *(const bf16x8*)&Wf[(size_t)((((w * 8 + ni) * 8 + kf) * 64 + lane) * 8)];
                acc[ni] = __builtin_amdgcn_mfma_f32_16x16x32_bf16(a, b, acc[ni], 0, 0, 0);
            }
        }
    };

    // mode 0: enc (Xl additive); 1: dec0 (l0w + cmd); 2: dec (biasf + cmd)
    auto epilogue = [&](int mode, int t) {
        float c0[4], c1[4];
        if (mode != 0) {
            #pragma unroll
            for (int r = 0; r < 4; ++r) {
                const int row = r0 + lhi * 4 + r;
                c0[r] = cmds[(size_t)row * (TN * CMDN) + t * CMDN];
                c1[r] = cmds[(size_t)row * (TN * CMDN) + t * CMDN + 1];
            }
        }
        const int nxt = cur ^ 1;
        #pragma unroll
        for (int ni = 0; ni < 8; ++ni) {
            const int p = w * 128 + ni * 16 + l15;
            #pragma unroll
            for (int r = 0; r < 4; ++r) {
                const int rw = lhi * 4 + r;
                float v = acc[ni][r];
                if (mode == 0)      v += b2f(Xl[rw * 1024 + p]);
                else if (mode == 1) v += l0w[(size_t)(r0 + rw) * NG + p]
                                       + c0[r] * w0_r[ni] + c1[r] * w1_r[ni];
                else                v += bf_r[ni]
                                       + c0[r] * w0_r[ni] + c1[r] * w1_r[ni];
                float act = (g == 2) ? tanhfa(v) : sigf(v);
                float a1  = __shfl_xor(act, 1);
                float a2  = __shfl_xor(act, 2);
                float a3  = __shfl_xor(act, 3);
                if (g == 0) {                    // lane holds i; a1=f, a2=g, a3=o
                    float cc = a1 * c_reg[ni][r] + act * a2;
                    c_reg[ni][r] = cc;
                    Hl[nxt][rw][p >> 2] = f2b(a3 * tanhfa(cc));
                }
            }
        }
    };

    // ---------------- encoder: 50 steps ----------------
    for (int t = 0; t < TN; ++t) {
        {   // stage xw slab (coalesced, issued before K-loop to hide latency)
            const unsigned short* xwt = xw + ((size_t)t * BATCH + r0) * NG;
            #pragma unroll
            for (int p4 = 0; p4 < 4; ++p4) {
                const int off = (p4 * 512 + tid) * 8;
                *(bf16x8*)&Xl[off] = *(const bf16x8*)&xwt[off];
            }
        }
        kloop(Wf_enc);
        __syncthreads();            // Xl visible to all waves
        epilogue(0, t);
        __syncthreads();            // Hl[nxt] complete
        cur ^= 1;
    }

    // ---------------- decoder: 50 steps ----------------
    for (int t = 0; t < TN; ++t) {
        kloop(t == 0 ? Wf_dec0 : Wf_dec);
        epilogue(t == 0 ? 1 : 2, t);
        __syncthreads();
        {   // coalesced copy Hl[nxt] -> hdec[t]
            const int rw2 = tid >> 5, k2 = (tid & 31) * 8;
            bf16x8 hv = *(const bf16x8*)&Hl[cur ^ 1][rw2][k2];
            *(bf16x8*)&hdec[((size_t)t * BATCH + r0 + rw2) * HN + k2] = hv;
        }
        cur ^= 1;
    }
}

// ---------------------------------------------------------------------------
// Packs / folds (one-time)
// ---------------------------------------------------------------------------
__global__ __launch_bounds__(256) void pack_w(
    const float* __restrict__ past,
    const float* __restrict__ eWih, const float* __restrict__ eb,
    const float* __restrict__ dWih, const float* __restrict__ db,
    const float* __restrict__ oW,
    unsigned short* __restrict__ L0b,      // [2048][384]
    unsigned short* __restrict__ Wihe_p,   // [1024][384] p-order
    unsigned short* __restrict__ Wdihl_p,  // [1024][384] p-order
    unsigned short* __restrict__ oWp,      // [384][256]
    float* __restrict__ Wc_p,              // [1024][2]
    float* __restrict__ ebp, float* __restrict__ dbp)
{
    int idx = blockIdx.x * 256 + threadIdx.x;
    if (idx < BATCH * KP) {                // L0b: lidar0 = past[:, -1, 2:]
        int b = idx / KP, k = idx - b * KP;
        L0b[idx] = (k < LIDARN)
            ? f2b(past[((size_t)b * TN + (TN - 1)) * KXN + CMDN + k]) : (unsigned short)0;
    }
    if (idx < NG * KP) {
        int p = idx / KP, k = idx - p * KP;
        int j = p2j(p);
        Wihe_p[idx]  = (k < KXN)    ? f2b(eWih[(size_t)j * KXN + k]) : (unsigned short)0;
        Wdihl_p[idx] = (k < LIDARN) ? f2b(dWih[(size_t)j * KXN + k]) : (unsigned short)0;
        if (k < 2) Wc_p[p * 2 + k] = dWih[(size_t)j * KXN + LIDARN + k];
        if (k == 0) { ebp[p] = eb[j]; dbp[p] = db[j]; }
    }
    if (idx < KP * HN) {
        int n = idx / HN, k = idx - n * HN;
        oWp[idx] = (n < LIDARN) ? f2b(oW[(size_t)n * HN + k]) : (unsigned short)0;
    }
}

// Wcomb_f[p][k] = dWhh[j][k] + sum_n dWih[j][n] * oW[n][k]   (f32, p-order)
__global__ __launch_bounds__(256) void wcomb_kernel(
    const float* __restrict__ dWih, const float* __restrict__ dWhh,
    const float* __restrict__ oW, float* __restrict__ Wcomb_f)
{
    int p = blockIdx.x, k = threadIdx.x;
    int j = p2j(p);
    float s = dWhh[(size_t)j * HN + k];
    for (int n = 0; n < LIDARN; ++n)
        s += dWih[(size_t)j * KXN + n] * oW[(size_t)n * HN + k];
    Wcomb_f[(size_t)p * HN + k] = s;
}

// biasf[p] = db[j] + sum_n dWih[j][n] * ob[n]
__global__ __launch_bounds__(256) void biasf_kernel(
    const float* __restrict__ dWih, const float* __restrict__ db,
    const float* __restrict__ ob, float* __restrict__ biasf)
{
    int p = blockIdx.x * 256 + threadIdx.x;
    if (p >= NG) return;
    int j = p2j(p);
    float s = db[j];
    for (int n = 0; n < LIDARN; ++n)
        s += dWih[(size_t)j * KXN + n] * ob[n];
    biasf[p] = s;
}

// Fragment-pack three recurrence weights:
// dst[((cf*8+kf)*64+lane)*8+e] = src[col=cf*16+(lane&15)][k=kf*32+(lane>>4)*8+e]
// sel 0: eWhh (j-order fp32), sel 1: dWhh (j-order), sel 2: Wcomb_f (p-order)
__global__ __launch_bounds__(256) void pack_wfrag(
    const float* __restrict__ eWhh, const float* __restrict__ dWhh,
    const float* __restrict__ Wcomb_f,
    unsigned short* __restrict__ Wf_enc,
    unsigned short* __restrict__ Wf_dec0,
    unsigned short* __restrict__ Wf_dec)
{
    const int NW = NG * HN;                      // 262144
    int idx = blockIdx.x * 256 + threadIdx.x;
    if (idx >= 3 * NW) return;
    int sel = idx / NW;
    int d   = idx - sel * NW;
    int e    = d & 7;
    int lane = (d >> 3) & 63;
    int kf   = (d >> 9) & 7;
    int cf   = d >> 12;
    int p = cf * 16 + (lane & 15);
    int k = kf * 32 + (lane >> 4) * 8 + e;
    if (sel == 0)      Wf_enc[d]  = f2b(eWhh[(size_t)p2j(p) * HN + k]);
    else if (sel == 1) Wf_dec0[d] = f2b(dWhh[(size_t)p2j(p) * HN + k]);
    else               Wf_dec[d]  = f2b(Wcomb_f[(size_t)p * HN + k]);
}

extern "C" void kernel_launch(void* const* d_in, const int* in_sizes, int n_in,
                              void* d_out, int out_size, void* d_ws, size_t ws_size,
                              hipStream_t stream)
{
    const float* past = (const float*)d_in[0];
    const float* cmds = (const float*)d_in[1];
    const float* eWih = (const float*)d_in[2];
    const float* eWhh = (const float*)d_in[3];
    const float* eb   = (const float*)d_in[4];
    const float* dWih = (const float*)d_in[5];
    const float* dWhh = (const float*)d_in[6];
    const float* db   = (const float*)d_in[7];
    const float* oW   = (const float*)d_in[8];
    const float* ob   = (const float*)d_in[9];
    float* out = (float*)d_out;

    char* w = (char*)d_ws;
    auto alloc = [&](size_t bytes) {
        char* p = w; w += (bytes + 255) & ~(size_t)255; return p;
    };
    unsigned short* xw      = (unsigned short*)alloc((size_t)MR * NG * 2);   // 209.7 MB
    unsigned short* hdec    = (unsigned short*)alloc((size_t)MR * HN * 2);   // 52.4 MB
    float*          l0w     = (float*)alloc((size_t)BATCH * NG * 4);         // 8.4 MB
    float*          Wcomb_f = (float*)alloc((size_t)NG * HN * 4);            // 1 MB
    unsigned short* Wf_enc  = (unsigned short*)alloc((size_t)NG * HN * 2);
    unsigned short* Wf_dec0 = (unsigned short*)alloc((size_t)NG * HN * 2);
    unsigned short* Wf_dec  = (unsigned short*)alloc((size_t)NG * HN * 2);
    unsigned short* L0b     = (unsigned short*)alloc((size_t)BATCH * KP * 2);
    unsigned short* Wihe_p  = (unsigned short*)alloc((size_t)NG * KP * 2);
    unsigned short* Wdihl_p = (unsigned short*)alloc((size_t)NG * KP * 2);
    unsigned short* oWp     = (unsigned short*)alloc((size_t)KP * HN * 2);
    float*          Wc_p    = (float*)alloc((size_t)NG * 2 * 4);
    float*          ebp     = (float*)alloc(NG * 4);
    float*          dbp     = (float*)alloc(NG * 4);
    float*          biasf   = (float*)alloc(NG * 4);

    pack_w<<<(BATCH * KP + 255) / 256, 256, 0, stream>>>(
        past, eWih, eb, dWih, db, oW,
        L0b, Wihe_p, Wdihl_p, oWp, Wc_p, ebp, dbp);
    wcomb_kernel<<<NG, 256, 0, stream>>>(dWih, dWhh, oW, Wcomb_f);
    biasf_kernel<<<(NG + 255) / 256, 256, 0, stream>>>(dWih, db, ob, biasf);
    pack_wfrag<<<(3 * NG * HN + 255) / 256, 256, 0, stream>>>(
        eWhh, dWhh, Wcomb_f, Wf_enc, Wf_dec0, Wf_dec);

    // xw = pack(past) @ Wihe^T + eb  (fused A-pack, bf16 out, t-major rows)
    gemm128<2, 1><<<dim3(NG / 128, MR / 128), 256, 0, stream>>>(
        nullptr, past, Wihe_p, ebp, xw, KP, NG);
    // l0w = lidar0 @ Wl^T + db (f32)
    gemm128<0, 0><<<dim3(NG / 128, BATCH / 128), 256, 0, stream>>>(
        L0b, nullptr, Wdihl_p, dbp, l0w, KP, NG);

    // all 100 recurrent steps: one regular kernel, zero cross-block sync
    recur_persist<<<BATCH / 16, 512, 0, stream>>>(
        xw, l0w, biasf, Wc_p, cmds, Wf_enc, Wf_dec0, Wf_dec, hdec);

    // out[b][t][n] = hdec[t][b] @ oW^T + ob
    gemm128<1, 0><<<dim3(KP / 128, MR / 128), 256, 0, stream>>>(
        hdec, nullptr, oWp, ob, out, HN, 0);
}